// Round 9
// baseline (232.804 us; speedup 1.0000x reference)
//
#include <hip/hip_runtime.h>
#include <math.h>

// LipsNet R9. B=8192, D_IN=256, H=256, D_OUT=64.
// k0: weight frags (R4/R7-validated layouts).
// k1: split-bf16 MFMA forward; S=8 samples/block, 256 thr, grid 1024 -> 4 blocks/CU,
//     shorter per-block serial path (R8 was grid-limited at 2 blocks/CU).
// k2: Jacobian; S=1 sample/block, 256 thr, grid 8192. Phase A removed: masked-W3
//     B-frags built in registers inside the ks loop (unroll 1 to prevent R5-style
//     hoist/spill). LDS = Vh only (32 KB) -> 4 blocks/CU for cross-block overlap
//     of the serial phases (R7/R8 plateau diagnosis).
//
// MFMA 16x16x32 layouts (validated R2/R4):
//   A[m][k]: m = lane&15, k = (lane>>4)*8 + i
//   B[k][n]: n = lane&15, k = (lane>>4)*8 + i
//   C/D:     col = lane&15, row = (lane>>4)*4 + reg

typedef float  f32x4  __attribute__((ext_vector_type(4)));
typedef short  bf16x8 __attribute__((ext_vector_type(8)));
typedef unsigned int   uint;
typedef unsigned short ushort;
typedef unsigned char  uchar;
typedef uint   u32x4  __attribute__((ext_vector_type(4)));
typedef uint   u32x2  __attribute__((ext_vector_type(2)));

// ws byte offsets
#define W2TA_OFF 0u        // 16rb x 8ks x 64l x 16B = 131072
#define W1TA_OFF 131072u   // 131072
#define W3A_OFF  262144u   // 32768 (k2 B-use AND k1 layer-3 hi A-frags)
#define F_OFF    294912u   // 8192x64 fp32 = 2097152
#define R1_OFF   2392064u  // 8192x256 u8 = 2097152
#define R2_OFF   4489216u  // 2097152
#define W1AH_OFF 6586368u  // 131072
#define W1AL_OFF 6717440u  // 131072
#define W2AH_OFF 6848512u  // 131072
#define W2AL_OFF 6979584u  // 131072
#define W3AL_OFF 7110656u  // 32768
// total 7143424 B

__device__ __forceinline__ ushort f2bf(float f) {
    uint u = __builtin_bit_cast(uint, f);
    u += 0x7FFFu + ((u >> 16) & 1u);          // RNE
    return (ushort)(u >> 16);
}
__device__ __forceinline__ float bf2f(ushort h) {
    uint u = ((uint)h) << 16;
    return __builtin_bit_cast(float, u);
}
// halfword and-mask from two mask bytes of u at bit positions sh, sh+8
__device__ __forceinline__ uint hm2(uint u, int sh) {
    return (((u >> sh) & 0xFFu)   ? 0xFFFFu     : 0u) |
           (((u >> sh) & 0xFF00u) ? 0xFFFF0000u : 0u);
}

// ---------------- k0: weight prep (R7-validated) ----------------
__global__ __launch_bounds__(256) void k0_prep(
    const float* __restrict__ W1, const float* __restrict__ W2,
    const float* __restrict__ W3, char* __restrict__ ws)
{
    const int id = blockIdx.x * 256 + threadIdx.x;
    if (id >= 34816) return;

    if (id < 16384) {
        // transposed A-frag gathers for k2
        const int fid = id & 8191;
        const int l = fid & 63, ks = (fid >> 6) & 7, rb = fid >> 9;
        const int m = l & 15, q = l >> 4;
        const int k0 = ks * 32 + q * 8;
        const float* M = (id < 8192) ? W2 : W1;
        const uint dstoff = (id < 8192) ? W2TA_OFF : W1TA_OFF;
        const int n = rb * 16 + m;
        ushort h[8];
        #pragma unroll
        for (int i = 0; i < 8; ++i) h[i] = f2bf(M[(k0 + i) * 256 + n]);
        u32x4 v;
        v.x = (uint)h[0] | ((uint)h[1] << 16);
        v.y = (uint)h[2] | ((uint)h[3] << 16);
        v.z = (uint)h[4] | ((uint)h[5] << 16);
        v.w = (uint)h[6] | ((uint)h[7] << 16);
        ((u32x4*)(ws + dstoff))[fid] = v;
        return;
    }

    // hi/lo A-frag pairs (row-major gathers) for k1 forward
    const float* M;
    uint hiOff, loOff;
    int fid;
    if (id < 18432)      { fid = id - 16384; M = W3; hiOff = W3A_OFF;  loOff = W3AL_OFF; }
    else if (id < 26624) { fid = id - 18432; M = W1; hiOff = W1AH_OFF; loOff = W1AL_OFF; }
    else                 { fid = id - 26624; M = W2; hiOff = W2AH_OFF; loOff = W2AL_OFF; }
    const int l = fid & 63, ks = (fid >> 6) & 7, rb = fid >> 9;
    const int m = l & 15, q = l >> 4;
    const int k0 = ks * 32 + q * 8;
    const float* p = M + (rb * 16 + m) * 256 + k0;
    ushort hh[8], ll[8];
    #pragma unroll
    for (int i = 0; i < 8; ++i) {
        const float v = p[i];
        const ushort h = f2bf(v);
        hh[i] = h;
        ll[i] = f2bf(v - bf2f(h));     // residual (exact subtraction)
    }
    u32x4 vh, vl;
    vh.x = (uint)hh[0] | ((uint)hh[1] << 16);
    vh.y = (uint)hh[2] | ((uint)hh[3] << 16);
    vh.z = (uint)hh[4] | ((uint)hh[5] << 16);
    vh.w = (uint)hh[6] | ((uint)hh[7] << 16);
    vl.x = (uint)ll[0] | ((uint)ll[1] << 16);
    vl.y = (uint)ll[2] | ((uint)ll[3] << 16);
    vl.z = (uint)ll[4] | ((uint)ll[5] << 16);
    vl.w = (uint)ll[6] | ((uint)ll[7] << 16);
    ((u32x4*)(ws + hiOff))[fid] = vh;
    ((u32x4*)(ws + loOff))[fid] = vl;
}

// ---------------- k1: split-bf16 MFMA forward, 8 samples/block, 256 thr ----------------
// Samples sit in MFMA columns m; columns 8..15 duplicate 0..7 (reads clamped m&7,
// stores guarded m<8). RBOF: row-block base for this wave (rb = RBOF + rr).
#define FWD_KLOOP(INOFF, HIOFF, LOOFF, NRB, RBOF, ACC)                             \
    {                                                                              \
        const bf16x8* WH = (const bf16x8*)(ws + (HIOFF));                          \
        const bf16x8* WL = (const bf16x8*)(ws + (LOOFF));                          \
        _Pragma("unroll")                                                          \
        for (int rr = 0; rr < (NRB); ++rr) ACC[rr] = (f32x4){0.f, 0.f, 0.f, 0.f};  \
        _Pragma("unroll")                                                          \
        for (int ks = 0; ks < 8; ++ks) {                                           \
            const int kk = ks * 32 + q * 8;                                        \
            float av[8];                                                           \
            *(f32x4*)&av[0] = *(const f32x4*)&SB[(INOFF) + (m & 7) * 260 + kk];    \
            *(f32x4*)&av[4] = *(const f32x4*)&SB[(INOFF) + (m & 7) * 260 + kk + 4];\
            uint hw[4], lw[4];                                                     \
            _Pragma("unroll")                                                      \
            for (int pp = 0; pp < 4; ++pp) {                                       \
                const float a0 = av[2 * pp], a1 = av[2 * pp + 1];                  \
                const ushort h0 = f2bf(a0), h1 = f2bf(a1);                         \
                const float r0 = a0 - bf2f(h0), r1 = a1 - bf2f(h1);                \
                hw[pp] = (uint)h0 | ((uint)h1 << 16);                              \
                lw[pp] = (uint)f2bf(r0) | ((uint)f2bf(r1) << 16);                  \
            }                                                                      \
            const bf16x8 bhi = __builtin_bit_cast(bf16x8, (u32x4){hw[0], hw[1], hw[2], hw[3]}); \
            const bf16x8 blo = __builtin_bit_cast(bf16x8, (u32x4){lw[0], lw[1], lw[2], lw[3]}); \
            _Pragma("unroll")                                                      \
            for (int rr = 0; rr < (NRB); ++rr) {                                   \
                const int rb = (RBOF) + rr;                                        \
                const bf16x8 ah = WH[(rb * 8 + ks) * 64 + l];                      \
                const bf16x8 al = WL[(rb * 8 + ks) * 64 + l];                      \
                ACC[rr] = __builtin_amdgcn_mfma_f32_16x16x32_bf16(ah, bhi, ACC[rr], 0, 0, 0); \
                ACC[rr] = __builtin_amdgcn_mfma_f32_16x16x32_bf16(al, bhi, ACC[rr], 0, 0, 0); \
                ACC[rr] = __builtin_amdgcn_mfma_f32_16x16x32_bf16(ah, blo, ACC[rr], 0, 0, 0); \
            }                                                                      \
        }                                                                          \
    }

__global__ __launch_bounds__(256) void k1_forward(
    const float* __restrict__ x,
    const float* __restrict__ b1, const float* __restrict__ b2,
    const float* __restrict__ b3, char* __restrict__ ws)
{
    __shared__ float SB[2 * 2080];   // [2][8 samples][260 fp32]; buf0: x then h2, buf1: h1
    const int t = threadIdx.x, w = t >> 6, l = t & 63;
    const int m = l & 15, q = l >> 4;
    const int g0 = blockIdx.x * 8;
    float* fws = (float*)(ws + F_OFF);
    uchar* r1g = (uchar*)(ws + R1_OFF);
    uchar* r2g = (uchar*)(ws + R2_OFF);

    // stage x (coalesced) into buf0
    {
        const f32x4* X4 = (const f32x4*)x;
        #pragma unroll
        for (int i = 0; i < 2; ++i) {
            const int idx = t + 256 * i;            // 0..511
            const int g = idx >> 6, dq = idx & 63;
            *(f32x4*)&SB[g * 260 + dq * 4] = X4[(size_t)(g0 + g) * 64 + dq];
        }
    }
    __syncthreads();

    f32x4 acc[4];

    // ---- layer 1: h1 = relu(W1 @ x) ; wave w owns rb in {4w..4w+3}
    FWD_KLOOP(0, W1AH_OFF, W1AL_OFF, 4, 4 * w, acc)
    #pragma unroll
    for (int rr = 0; rr < 4; ++rr) {
        const int i0 = (4 * w + rr) * 16 + q * 4;
        const float4 bv = *(const float4*)(b1 + i0);
        const float v0 = acc[rr].x + bv.x, v1 = acc[rr].y + bv.y;
        const float v2 = acc[rr].z + bv.z, v3 = acc[rr].w + bv.w;
        if (m < 8) {
            const uint mv = (v0 > 0.f ? 1u : 0u) | (v1 > 0.f ? 0x100u : 0u) |
                            (v2 > 0.f ? 0x10000u : 0u) | (v3 > 0.f ? 0x1000000u : 0u);
            *(uint*)(r1g + (size_t)(g0 + m) * 256 + i0) = mv;
            const f32x4 rv = {fmaxf(v0, 0.f), fmaxf(v1, 0.f), fmaxf(v2, 0.f), fmaxf(v3, 0.f)};
            *(f32x4*)&SB[2080 + m * 260 + i0] = rv;
        }
    }
    __syncthreads();

    // ---- layer 2: h2 = relu(W2 @ h1) ; -> buf0 (overlay x)
    FWD_KLOOP(2080, W2AH_OFF, W2AL_OFF, 4, 4 * w, acc)
    #pragma unroll
    for (int rr = 0; rr < 4; ++rr) {
        const int i0 = (4 * w + rr) * 16 + q * 4;
        const float4 bv = *(const float4*)(b2 + i0);
        const float v0 = acc[rr].x + bv.x, v1 = acc[rr].y + bv.y;
        const float v2 = acc[rr].z + bv.z, v3 = acc[rr].w + bv.w;
        if (m < 8) {
            const uint mv = (v0 > 0.f ? 1u : 0u) | (v1 > 0.f ? 0x100u : 0u) |
                            (v2 > 0.f ? 0x10000u : 0u) | (v3 > 0.f ? 0x1000000u : 0u);
            *(uint*)(r2g + (size_t)(g0 + m) * 256 + i0) = mv;
            const f32x4 rv = {fmaxf(v0, 0.f), fmaxf(v1, 0.f), fmaxf(v2, 0.f), fmaxf(v3, 0.f)};
            *(f32x4*)&SB[m * 260 + i0] = rv;
        }
    }
    __syncthreads();

    // ---- layer 3: f = W3 @ h2 ; wave w owns row-block w
    FWD_KLOOP(0, W3A_OFF, W3AL_OFF, 1, w, acc)
    if (m < 8) {
        const int j0 = w * 16 + q * 4;
        const float4 bv = *(const float4*)(b3 + j0);
        const f32x4 ov = {acc[0].x + bv.x, acc[0].y + bv.y, acc[0].z + bv.z, acc[0].w + bv.w};
        *(f32x4*)(fws + (size_t)(g0 + m) * 64 + j0) = ov;
    }
}

// ---------------- k2: Jacobian norm + output, 1 sample/block, 256 thr ----------------
__global__ __launch_bounds__(256, 4) void k2_jac(
    const char* __restrict__ ws, const float* __restrict__ kp,
    float* __restrict__ out)
{
    __shared__ ushort Vh[16384];           // 32 KB, XOR-swizzled rows (R4-validated addressing)
    __shared__ uint r1u[64], r2u[64];
    __shared__ float red[4];

    const int t = threadIdx.x, w = t >> 6, l = t & 63;
    const int m = l & 15, q = l >> 4;
    const int b = blockIdx.x;

    if (t < 64)       r1u[t]      = ((const uint*)(ws + R1_OFF))[(size_t)b * 64 + t];
    else if (t < 128) r2u[t - 64] = ((const uint*)(ws + R2_OFF))[(size_t)b * 64 + (t - 64)];
    __syncthreads();

    // ---- GEMM1: A1^T = W2T @ (W3 .* r2)^T ; masked-W3 B-frags built in registers.
    //      unroll 1 keeps loads scoped (R5's spill came from full-unroll hoisting).
    f32x4 acc[4][4];                       // [rp][cb]
    #pragma unroll
    for (int rp = 0; rp < 4; ++rp)
        #pragma unroll
        for (int cb = 0; cb < 4; ++cb) acc[rp][cb] = (f32x4){0.f, 0.f, 0.f, 0.f};

    {
        const bf16x8* W2Tf = (const bf16x8*)(ws + W2TA_OFF);
        const u32x4*  W3Av = (const u32x4*)(ws + W3A_OFF);
        #pragma unroll 1
        for (int ks = 0; ks < 8; ++ks) {
            bf16x8 a[4];
            #pragma unroll
            for (int rp = 0; rp < 4; ++rp) a[rp] = W2Tf[((4 * w + rp) * 8 + ks) * 64 + l];
            const int du = ks * 8 + q * 2;          // r2 word idx for d = ks*32+q*8
            const uint u0 = r2u[du], u1 = r2u[du + 1];
            const uint mw0 = hm2(u0, 0), mw1 = hm2(u0, 16);
            const uint mw2 = hm2(u1, 0), mw3 = hm2(u1, 16);
            #pragma unroll
            for (int cb = 0; cb < 4; ++cb) {
                u32x4 v = W3Av[(cb * 8 + ks) * 64 + l];
                v.x &= mw0; v.y &= mw1; v.z &= mw2; v.w &= mw3;
                const bf16x8 bb = __builtin_bit_cast(bf16x8, v);
                #pragma unroll
                for (int rp = 0; rp < 4; ++rp)
                    acc[rp][cb] = __builtin_amdgcn_mfma_f32_16x16x32_bf16(a[rp], bb, acc[rp][cb], 0, 0, 0);
            }
        }
    }

    // ---- Phase C: Vh[j][e] = A1^T[e][j] * r1[e] (bf16, XOR-swizzled, b64 writes)
    {
        #pragma unroll
        for (int rp = 0; rp < 4; ++rp) {
            const int rb = 4 * w + rp;
            const int e0 = rb * 16 + q * 4;
            const uint mu = r1u[rb * 4 + q];
            #pragma unroll
            for (int cb = 0; cb < 4; ++cb) {
                const f32x4 av = acc[rp][cb];
                const float v0 = (mu & 0xFFu)       ? av.x : 0.f;
                const float v1 = (mu & 0xFF00u)     ? av.y : 0.f;
                const float v2 = (mu & 0xFF0000u)   ? av.z : 0.f;
                const float v3 = (mu & 0xFF000000u) ? av.w : 0.f;
                u32x2 p;
                p.x = (uint)f2bf(v0) | ((uint)f2bf(v1) << 16);
                p.y = (uint)f2bf(v2) | ((uint)f2bf(v3) << 16);
                const int j = cb * 16 + m;
                const int idx = j * 256 + (e0 ^ ((j & 7) << 3));
                *(u32x2*)&Vh[idx] = p;
            }
        }
    }
    __syncthreads();

    // ---- GEMM2: M^T = W1T @ (Vh as B) ; wave w owns rb_n in {4w..4w+3}
    f32x4 acc2[4][4];
    #pragma unroll
    for (int rp = 0; rp < 4; ++rp)
        #pragma unroll
        for (int cb = 0; cb < 4; ++cb) acc2[rp][cb] = (f32x4){0.f, 0.f, 0.f, 0.f};

    {
        const bf16x8* W1Tf = (const bf16x8*)(ws + W1TA_OFF);
        #pragma unroll 1
        for (int ks = 0; ks < 8; ++ks) {
            bf16x8 a[4];
            #pragma unroll
            for (int rp = 0; rp < 4; ++rp) a[rp] = W1Tf[((4 * w + rp) * 8 + ks) * 64 + l];
            const int c0 = ks * 32 + q * 8;
            #pragma unroll
            for (int cb = 0; cb < 4; ++cb) {
                const int j = cb * 16 + m;
                const bf16x8 bb = *(const bf16x8*)&Vh[j * 256 + (c0 ^ ((j & 7) << 3))];
                #pragma unroll
                for (int rp = 0; rp < 4; ++rp)
                    acc2[rp][cb] = __builtin_amdgcn_mfma_f32_16x16x32_bf16(a[rp], bb, acc2[rp][cb], 0, 0, 0);
            }
        }
    }

    // ---- reduce ||M||_F^2
    {
        float ps = 0.f;
        #pragma unroll
        for (int rp = 0; rp < 4; ++rp)
            #pragma unroll
            for (int cb = 0; cb < 4; ++cb) {
                const f32x4 a0 = acc2[rp][cb];
                ps = fmaf(a0.x, a0.x, ps); ps = fmaf(a0.y, a0.y, ps);
                ps = fmaf(a0.z, a0.z, ps); ps = fmaf(a0.w, a0.w, ps);
            }
        #pragma unroll
        for (int off = 32; off > 0; off >>= 1) ps += __shfl_down(ps, off, 64);
        if (l == 0) red[w] = ps;
    }
    __syncthreads();

    if (t < 64) {
        const float S = red[0] + red[1] + red[2] + red[3];
        const float* fws = (const float*)(ws + F_OFF);
        const float f = fws[(size_t)b * 64 + t];
        const float kv = kp[0];
        const float ksp = fmaxf(kv, 0.0f) + log1pf(expf(-fabsf(kv)));
        out[(size_t)b * 64 + t] = tanhf(ksp * f / (sqrtf(S) + 1e-4f));
    }
}

extern "C" void kernel_launch(void* const* d_in, const int* in_sizes, int n_in,
                              void* d_out, int out_size, void* d_ws, size_t ws_size,
                              hipStream_t stream) {
    const float* x  = (const float*)d_in[0];
    const float* W1 = (const float*)d_in[1];
    const float* b1 = (const float*)d_in[2];
    const float* W2 = (const float*)d_in[3];
    const float* b2 = (const float*)d_in[4];
    const float* W3 = (const float*)d_in[5];
    const float* b3 = (const float*)d_in[6];
    const float* kp = (const float*)d_in[7];
    char* ws = (char*)d_ws;

    k0_prep<<<136, 256, 0, stream>>>(W1, W2, W3, ws);
    k1_forward<<<1024, 256, 0, stream>>>(x, b1, b2, b3, ws);
    k2_jac<<<8192, 256, 0, stream>>>(ws, kp, (float*)d_out);
}